// Round 9
// baseline (201.959 us; speedup 1.0000x reference)
//
#include <hip/hip_runtime.h>
#include <hip/hip_bf16.h>

#define TT    512
#define ISZ   9
#define HH    50
#define NB    16      // batches per block
#define NWAVE 14      // waves 0-12: one 16-row tile each; wave 13: x staging
#define NTH   (NWAVE * 64)   // 896 threads
#define KDIM  64
// K layout (f16, per batch-column), buffer stride 128 B, toggle ^0x800:
//   k=j      : h_j f16 (j=0..49)
//   k=50+i   : x_i f16 (i=0..8)
//   k=59..63 : zero pad (A zero there; dead cells j=50,51 dump to k=59,60)
// Bias is carried in the MFMA C-input (exact f32, pre-scaled).

typedef _Float16 f16x8_t __attribute__((ext_vector_type(8)));
typedef float    f32x4_t __attribute__((ext_vector_type(4)));

#define L2E   1.44269504088896340736f
#define TWOL2E 2.88539008177792681472f

// barrier draining ONLY lgkmcnt (ds ops) — vmcnt (x prefetch) stays in flight
#define BAR() asm volatile("s_waitcnt lgkmcnt(0)\n\ts_barrier" ::: "memory")

__device__ __forceinline__ unsigned short f16h(float v) {
  _Float16 b = (_Float16)v;
  return __builtin_bit_cast(unsigned short, b);
}
__device__ __forceinline__ float sg_exp2(float z) { return __builtin_amdgcn_exp2f(z); }
__device__ __forceinline__ float rcp_f(float z)   { return __builtin_amdgcn_rcpf(z); }

__global__ __launch_bounds__(NTH, 1) void lstm_mfma(
    const float* __restrict__ x,
    const float* __restrict__ w_ih,
    const float* __restrict__ w_hh,
    const float* __restrict__ b_ih,
    const float* __restrict__ b_hh,
    const float* __restrict__ fc_w,
    const float* __restrict__ fc_b,
    float* __restrict__ out) {
  __shared__ __align__(16) unsigned short hbuf[2][NB * KDIM];  // 2 x 2048 B
  __shared__ float redbuf[NWAVE][NB];

  const int tid = threadIdx.x;
  const int w   = tid >> 6;          // wave id; w<13 = compute (tile w), w=13 = x-stager
  const int l   = tid & 63;
  const int lb  = l & 15;            // batch column
  const int kq  = l >> 4;            // k-quarter 0..3
  const int b0  = blockIdx.x * NB;
  const bool cw = (w < 13);

  // ---- zero both h buffers
  for (int i = tid; i < (2 * NB * KDIM) / 2; i += NTH)
    reinterpret_cast<unsigned*>(hbuf)[i] = 0u;

  // x-stager mapping: wave 13, lanes 0-47, 3 elements each (l, l+48, l+96)
  const bool sw = (w == 13) && (l < 48);
  int xb_[3], xi_[3], xwo_[3];
  const float* xp_[3];
#pragma unroll
  for (int k = 0; k < 3; ++k) {
    const int e = l + 48 * k;
    xb_[k] = sw ? (e / ISZ) : 0;
    xi_[k] = sw ? (e - xb_[k] * ISZ) : 0;
    xwo_[k] = (((xb_[k] << 7) + ((50 + xi_[k]) << 1)) ^ ((xb_[k] & 7) << 4));
    xp_[k] = x + (size_t)(b0 + xb_[k]) * (TT * ISZ) + xi_[k];
  }
  __syncthreads();
  // ---- x(t=0) into buf0
  if (sw) {
#pragma unroll
    for (int k = 0; k < 3; ++k)
      *(unsigned short*)((char*)hbuf[0] + xwo_[k]) = f16h(*xp_[k]);
  }

  // ---- static A fragment (tile w), f16, weights pre-scaled:
  //   i,f,o rows: * -log2e ; g row: * 2log2e
  // Row permutation rp = 4j+g so lane's 4 acc regs = (i,f,g,o) of one j.
  f16x8_t afrag[2];
  {
    const int rp   = w * 16 + lb;
    const int jA   = rp >> 2;
    const int gA   = rp & 3;
    const int rowA = gA * HH + jA;
    const bool liveA = cw && (jA < HH);
    const float scA = (gA == 2) ? TWOL2E : (-L2E);
#pragma unroll
    for (int ks = 0; ks < 2; ++ks) {
#pragma unroll
      for (int e = 0; e < 8; ++e) {
        const int K = ks * 32 + kq * 8 + e;
        float v = 0.0f;
        if (liveA) {
          if (K < HH)            v = w_hh[rowA * HH + K] * scA;
          else if (K < HH + ISZ) v = w_ih[rowA * ISZ + (K - HH)] * scA;
        }
        afrag[ks][e] = (_Float16)v;
      }
    }
  }

  // ---- per-lane bias C-init (exact f32, pre-scaled) for cell (j0, lb)
  const int j0 = w * 4 + kq;
  const bool live0 = cw && (j0 < HH);
  f32x4_t bias0 = {0.f, 0.f, 0.f, 0.f};
  if (live0) {
#pragma unroll
    for (int r = 0; r < 4; ++r) {
      const float sc = (r == 2) ? TWOL2E : (-L2E);
      bias0[r] = (b_ih[r * HH + j0] + b_hh[r * HH + j0]) * sc;
    }
  }

  // ---- loop-invariant LDS byte addresses (buf0-relative; buf1 = +0x800 imm)
  char* const base = (char*)hbuf[0];
  const int swzb = (lb & 7) << 4;
  const int rd0 = ((lb << 7) + 0  + (kq << 4)) ^ swzb;
  const int rd1 = ((lb << 7) + 64 + (kq << 4)) ^ swzb;
  const int j0c = (j0 < HH) ? j0 : (j0 + 9);      // dead j 50,51 -> pad cols 59,60
  const int wo0 = (((lb << 7) + (j0c << 1)) ^ swzb);

  float csc = 0.0f, h0 = 0.0f;       // csc = c * 2*L2E (pre-scaled cell state)
  float xv_n[3] = {0.f, 0.f, 0.f};   // x(t+1); prefetch depth 2
  if (sw) {
#pragma unroll
    for (int k = 0; k < 3; ++k) { xv_n[k] = xp_[k][ISZ]; xp_[k] += 2 * ISZ; }
  }

#define STEP(T, ROFF, WOFF)                                                      \
  if (cw) {                                                                      \
    BAR();                                                                       \
    __builtin_amdgcn_s_setprio(1);                                               \
    f16x8_t bb0 = *(const f16x8_t*)(base + rd0 + (ROFF));                        \
    f16x8_t bb1 = *(const f16x8_t*)(base + rd1 + (ROFF));                        \
    f32x4_t acc;                                                                 \
    acc = __builtin_amdgcn_mfma_f32_16x16x32_f16(afrag[0], bb0, bias0, 0,0,0);   \
    acc = __builtin_amdgcn_mfma_f32_16x16x32_f16(afrag[1], bb1, acc,   0,0,0);   \
    __builtin_amdgcn_s_setprio(0);                                               \
    const float pi = sg_exp2(acc[0]);   /* e^-zi  */                             \
    const float pf = sg_exp2(acc[1]);   /* e^-zf  */                             \
    const float eg = sg_exp2(acc[2]);   /* e^+2zg */                             \
    const float po = sg_exp2(acc[3]);   /* e^-zo  */                             \
    const float A1 = 1.0f + pi, A2 = 1.0f + eg, A3 = 1.0f + pf;                  \
    const float P  = A1 * A2;                                                    \
    const float R  = rcp_f(P * A3);                                              \
    const float u  = (eg - 1.0f) * TWOL2E;                                       \
    const float fv = P * R;             /* 1/(1+pf) */                           \
    const float ig2 = u * (A3 * R);     /* 2L2E * i*g */                         \
    csc = fmaf(fv, csc, ig2);           /* csc = 2*L2E*c */                      \
    const float ec = sg_exp2(csc);                                               \
    const float r2 = rcp_f((1.0f + po) * (1.0f + ec));                           \
    h0 = (ec - 1.0f) * r2;                                                       \
    *(unsigned short*)(base + wo0 + (WOFF)) = f16h(h0);                          \
  } else {                                                                       \
    float xnew[3] = {0.f, 0.f, 0.f};                                             \
    if (sw && (T) + 2 < TT) {                                                    \
      xnew[0] = *xp_[0]; xnew[1] = *xp_[1]; xnew[2] = *xp_[2];                   \
    }                                                                            \
    if (sw) { xp_[0] += ISZ; xp_[1] += ISZ; xp_[2] += ISZ; }                     \
    BAR();                                                                       \
    if (sw && (T) + 1 < TT) {                                                    \
      *(unsigned short*)(base + xwo_[0] + (WOFF)) = f16h(xv_n[0]);               \
      *(unsigned short*)(base + xwo_[1] + (WOFF)) = f16h(xv_n[1]);               \
      *(unsigned short*)(base + xwo_[2] + (WOFF)) = f16h(xv_n[2]);               \
    }                                                                            \
    xv_n[0] = xnew[0]; xv_n[1] = xnew[1]; xv_n[2] = xnew[2];                     \
  }

  for (int t2 = 0; t2 < TT; t2 += 2) {
    STEP(t2,     0x000, 0x800);   // read buf0, write buf1
    STEP(t2 + 1, 0x800, 0x000);   // read buf1, write buf0
  }
#undef STEP

  // ---- FC epilogue: out[b] = sum_j h_last[j,b]*fc_w[j] + fc_b
  float p = live0 ? h0 * fc_w[j0] : 0.0f;
  p += __shfl_xor(p, 16);
  p += __shfl_xor(p, 32);
  if (l < NB) redbuf[w][l] = p;
  __syncthreads();
  if (tid < NB) {
    float a = fc_b[0];
#pragma unroll
    for (int ww = 0; ww < NWAVE; ++ww) a += redbuf[ww][tid];
    out[b0 + tid] = a;
  }
}

extern "C" void kernel_launch(void* const* d_in, const int* in_sizes, int n_in,
                              void* d_out, int out_size, void* d_ws, size_t ws_size,
                              hipStream_t stream) {
  const float* x    = (const float*)d_in[0];
  const float* w_ih = (const float*)d_in[1];
  const float* w_hh = (const float*)d_in[2];
  const float* b_ih = (const float*)d_in[3];
  const float* b_hh = (const float*)d_in[4];
  const float* fc_w = (const float*)d_in[5];
  const float* fc_b = (const float*)d_in[6];
  float* out = (float*)d_out;
  const int Btot = in_sizes[0] / (TT * ISZ);   // 4096
  dim3 grid(Btot / NB), block(NTH);
  hipLaunchKernelGGL(lstm_mfma, grid, block, 0, stream,
                     x, w_ih, w_hh, b_ih, b_hh, fc_w, fc_b, out);
}

// Round 10
// 186.569 us; speedup vs baseline: 1.0825x; 1.0825x over previous
//
#include <hip/hip_runtime.h>
#include <hip/hip_bf16.h>

#define TT    512
#define ISZ   9
#define HH    50
#define NB    16      // batches per block
#define NWAVE 16      // waves 0-12: one 16-row tile each; waves 13-15: x staging
#define NTH   (NWAVE * 64)   // 1024 threads
#define KDIM  64
// K layout (f16, per batch-column), buffer stride 128 B, toggle ^0x800:
//   k=j      : h_j f16 (j=0..49)
//   k=50+i   : x_i f16 (i=0..8)
//   k=59..63 : zero pad (A zero there; dead cells j=50,51 dump to k=59,60)
// Bias is carried in the MFMA C-input (exact f32, pre-scaled).

typedef _Float16 f16x8_t __attribute__((ext_vector_type(8)));
typedef float    f32x4_t __attribute__((ext_vector_type(4)));

#define L2E    1.44269504088896340736f
#define TWOL2E 2.88539008177792681472f

// barrier draining ONLY lgkmcnt (ds ops) — vmcnt (x prefetch) stays in flight
#define BAR() asm volatile("s_waitcnt lgkmcnt(0)\n\ts_barrier" ::: "memory")

__device__ __forceinline__ unsigned short f16h(float v) {
  _Float16 b = (_Float16)v;
  return __builtin_bit_cast(unsigned short, b);
}
__device__ __forceinline__ float sg_exp2(float z) { return __builtin_amdgcn_exp2f(z); }
__device__ __forceinline__ float rcp_f(float z)   { return __builtin_amdgcn_rcpf(z); }

__global__ __launch_bounds__(NTH, 1) void lstm_mfma(
    const float* __restrict__ x,
    const float* __restrict__ w_ih,
    const float* __restrict__ w_hh,
    const float* __restrict__ b_ih,
    const float* __restrict__ b_hh,
    const float* __restrict__ fc_w,
    const float* __restrict__ fc_b,
    float* __restrict__ out) {
  __shared__ __align__(16) unsigned short hbuf[2][NB * KDIM];  // 2 x 2048 B
  __shared__ float redbuf[NWAVE][NB];

  const int tid = threadIdx.x;
  const int w   = tid >> 6;          // wave id; w<13 = compute (tile w), w>=13 = x-stager
  const int l   = tid & 63;
  const int lb  = l & 15;            // batch column
  const int kq  = l >> 4;            // k-quarter 0..3
  const int b0  = blockIdx.x * NB;
  const bool cw = (w < 13);

  // ---- zero both h buffers
  for (int i = tid; i < (2 * NB * KDIM) / 2; i += NTH)
    reinterpret_cast<unsigned*>(hbuf)[i] = 0u;

  // x-stager mapping (waves 13-15: 192 lanes, 144 active)
  const int xt = tid - 13 * 64;
  const bool xact = (xt >= 0 && xt < NB * ISZ);
  const int xb = xact ? (xt / ISZ) : 0;
  const int xi = xact ? (xt - xb * ISZ) : 0;
  __syncthreads();
  // ---- x(t=0) into buf0
  if (xact) {
    float xv = x[(size_t)(b0 + xb) * (TT * ISZ) + xi];
    *(unsigned short*)((char*)hbuf[0] + (((xb << 7) + ((50 + xi) << 1)) ^ ((xb & 7) << 4))) = f16h(xv);
  }

  // ---- static A fragment (tile w), f16, weights pre-scaled:
  //   i,f,o rows: * -log2e ; g row: * 2log2e
  // Row permutation rp = 4j+g so lane's 4 acc regs = (i,f,g,o) of one j.
  f16x8_t afrag[2];
  {
    const int rp   = w * 16 + lb;
    const int jA   = rp >> 2;
    const int gA   = rp & 3;
    const int rowA = gA * HH + jA;
    const bool liveA = cw && (jA < HH);
    const float scA = (gA == 2) ? TWOL2E : (-L2E);
#pragma unroll
    for (int ks = 0; ks < 2; ++ks) {
#pragma unroll
      for (int e = 0; e < 8; ++e) {
        const int K = ks * 32 + kq * 8 + e;
        float v = 0.0f;
        if (liveA) {
          if (K < HH)            v = w_hh[rowA * HH + K] * scA;
          else if (K < HH + ISZ) v = w_ih[rowA * ISZ + (K - HH)] * scA;
        }
        afrag[ks][e] = (_Float16)v;
      }
    }
  }

  // ---- per-lane bias C-init (exact f32, pre-scaled) for cell (j0, lb)
  const int j0 = w * 4 + kq;
  const bool live0 = cw && (j0 < HH);
  f32x4_t bias0 = {0.f, 0.f, 0.f, 0.f};
  if (live0) {
#pragma unroll
    for (int r = 0; r < 4; ++r) {
      const float sc = (r == 2) ? TWOL2E : (-L2E);
      bias0[r] = (b_ih[r * HH + j0] + b_hh[r * HH + j0]) * sc;
    }
  }

  // ---- loop-invariant LDS byte addresses (buf0-relative; buf1 = +0x800 imm)
  char* const base = (char*)hbuf[0];
  const int swzb = (lb & 7) << 4;
  const int rd0 = ((lb << 7) + 0  + (kq << 4)) ^ swzb;
  const int rd1 = ((lb << 7) + 64 + (kq << 4)) ^ swzb;
  const int j0c = (j0 < HH) ? j0 : (j0 + 9);      // dead j 50,51 -> pad cols 59,60
  const int wo0 = (((lb << 7) + (j0c << 1)) ^ swzb);
  const int xwo = (((xb << 7) + ((50 + xi) << 1)) ^ ((xb & 7) << 4));

  const float* xp = x + (size_t)(b0 + xb) * (TT * ISZ) + xi;
  float csc = 0.0f, h0 = 0.0f;       // csc = c * 2*L2E (pre-scaled cell state)
  float xv_n = 0.0f;                 // x(t+1); prefetch depth 2
  if (xact) xv_n = xp[ISZ];
  xp += 2 * ISZ;

#define STEP(T, ROFF, WOFF)                                                      \
  if (cw) {                                                                      \
    BAR();                                                                       \
    f16x8_t bb0 = *(const f16x8_t*)(base + rd0 + (ROFF));                        \
    f16x8_t bb1 = *(const f16x8_t*)(base + rd1 + (ROFF));                        \
    f32x4_t acc;                                                                 \
    acc = __builtin_amdgcn_mfma_f32_16x16x32_f16(afrag[0], bb0, bias0, 0,0,0);   \
    acc = __builtin_amdgcn_mfma_f32_16x16x32_f16(afrag[1], bb1, acc,   0,0,0);   \
    const float pi = sg_exp2(acc[0]);   /* e^-zi  */                             \
    const float pf = sg_exp2(acc[1]);   /* e^-zf  */                             \
    const float eg = sg_exp2(acc[2]);   /* e^+2zg */                             \
    const float po = sg_exp2(acc[3]);   /* e^-zo  */                             \
    const float A1 = 1.0f + pi, A2 = 1.0f + eg, A3 = 1.0f + pf;                  \
    const float P  = A1 * A2;                                                    \
    const float R  = rcp_f(P * A3);                                              \
    const float u  = (eg - 1.0f) * TWOL2E;                                       \
    const float fv = P * R;             /* 1/(1+pf) */                           \
    const float ig2 = u * (A3 * R);     /* 2L2E * i*g */                         \
    csc = fmaf(fv, csc, ig2);           /* csc = 2*L2E*c */                      \
    const float ec = sg_exp2(csc);                                               \
    const float r2 = rcp_f((1.0f + po) * (1.0f + ec));                           \
    h0 = (ec - 1.0f) * r2;                                                       \
    *(unsigned short*)(base + wo0 + (WOFF)) = f16h(h0);                          \
  } else {                                                                       \
    float xv_new = 0.0f;                                                         \
    if (xact && (T) + 2 < TT) xv_new = *xp;                                      \
    xp += ISZ;                                                                   \
    BAR();                                                                       \
    if (xact && (T) + 1 < TT) *(unsigned short*)(base + xwo + (WOFF)) = f16h(xv_n); \
    xv_n = xv_new;                                                               \
  }

  for (int t2 = 0; t2 < TT; t2 += 2) {
    STEP(t2,     0x000, 0x800);   // read buf0, write buf1
    STEP(t2 + 1, 0x800, 0x000);   // read buf1, write buf0
  }
#undef STEP

  // ---- FC epilogue: out[b] = sum_j h_last[j,b]*fc_w[j] + fc_b
  float p = live0 ? h0 * fc_w[j0] : 0.0f;
  p += __shfl_xor(p, 16);
  p += __shfl_xor(p, 32);
  if (l < NB) redbuf[w][l] = p;
  __syncthreads();
  if (tid < NB) {
    float a = fc_b[0];
#pragma unroll
    for (int ww = 0; ww < NWAVE; ++ww) a += redbuf[ww][tid];
    out[b0 + tid] = a;
  }
}

extern "C" void kernel_launch(void* const* d_in, const int* in_sizes, int n_in,
                              void* d_out, int out_size, void* d_ws, size_t ws_size,
                              hipStream_t stream) {
  const float* x    = (const float*)d_in[0];
  const float* w_ih = (const float*)d_in[1];
  const float* w_hh = (const float*)d_in[2];
  const float* b_ih = (const float*)d_in[3];
  const float* b_hh = (const float*)d_in[4];
  const float* fc_w = (const float*)d_in[5];
  const float* fc_b = (const float*)d_in[6];
  float* out = (float*)d_out;
  const int Btot = in_sizes[0] / (TT * ISZ);   // 4096
  dim3 grid(Btot / NB), block(NTH);
  hipLaunchKernelGGL(lstm_mfma, grid, block, 0, stream,
                     x, w_ih, w_hh, b_ih, b_hh, fc_w, fc_b, out);
}